// Round 5
// baseline (398.994 us; speedup 1.0000x reference)
//
#include <hip/hip_runtime.h>

#define NUSER 100000
#define NITEM 50000
#define NTOT  150000
#define DF    512
#define DL    64
#define NNZ_  2400000
#define NB    1172        // ceil(150000/128) row-bins of 128 rows
#define NCHUNK 256
#define CHUNK  9375       // 256*9375 = 2,400,000 exactly

__device__ __forceinline__ unsigned short bf16r(float f) {
    unsigned u = __float_as_uint(f);
    return (unsigned short)((u + 0x7FFFu + ((u >> 16) & 1u)) >> 16);
}
__device__ __forceinline__ unsigned pack2(float lo, float hi) {
    return (unsigned)bf16r(lo) | ((unsigned)bf16r(hi) << 16);
}

// ---------------- users: L2-normalize rows -> e0 (bf16) ----------------
__global__ __launch_bounds__(256) void k_user(const float* __restrict__ up,
                                              unsigned short* __restrict__ e0) {
    int t = blockIdx.x * 256 + threadIdx.x;
    float v = up[t];
    float ss = v * v;
    #pragma unroll
    for (int m = 32; m >= 1; m >>= 1) ss += __shfl_xor(ss, m, 64);
    float scale = 1.0f / fmaxf(sqrtf(ss), 1e-12f);
    e0[t] = bf16r(v * scale);
}

// ---------------- items: GEMM 64x64 tile, 512 threads (2 rows x 4 dims each) ----------------
#define KCH 64
__global__ __launch_bounds__(512) void k_item(const float* __restrict__ F,
                                              const float* __restrict__ W,
                                              const float* __restrict__ B,
                                              unsigned short* __restrict__ e0) {
    __shared__ float ft[64][66];
    __shared__ float wt[KCH][64];
    int t = threadIdx.x;
    int block_r0 = blockIdx.x * 64;
    int d0 = (t & 15) * 4;
    int r0 = (t >> 4) * 2;          // 32 row-groups x 2 rows
    float acc[2][4] = {};
    for (int kc = 0; kc < DF; kc += KCH) {
        // stage F tile: 64 rows x 64 k (1024 float4, 2 per thread)
        #pragma unroll
        for (int i = 0; i < 2; ++i) {
            int li  = t + i * 512;
            int row = li >> 4;
            int k4  = (li & 15) * 4;
            int gr  = block_r0 + row;
            float4 v = make_float4(0.f, 0.f, 0.f, 0.f);
            if (gr < NITEM) v = *(const float4*)&F[(size_t)gr * DF + kc + k4];
            *(float4*)&ft[row][k4] = v;
        }
        // stage W chunk: 64 k x 64 d (1024 float4, 2 per thread)
        #pragma unroll
        for (int i = 0; i < 2; ++i) {
            int li = t + i * 512;
            int k  = li >> 4;
            int dd = (li & 15) * 4;
            *(float4*)&wt[k][dd] = *(const float4*)&W[(size_t)(kc + k) * DL + dd];
        }
        __syncthreads();
        #pragma unroll 4
        for (int kk = 0; kk < KCH; kk += 4) {
            float4 w0 = *(const float4*)&wt[kk + 0][d0];
            float4 w1 = *(const float4*)&wt[kk + 1][d0];
            float4 w2 = *(const float4*)&wt[kk + 2][d0];
            float4 w3 = *(const float4*)&wt[kk + 3][d0];
            #pragma unroll
            for (int i = 0; i < 2; ++i) {
                float4 f = *(const float4*)&ft[r0 + i][kk];
                acc[i][0] += f.x * w0.x + f.y * w1.x + f.z * w2.x + f.w * w3.x;
                acc[i][1] += f.x * w0.y + f.y * w1.y + f.z * w2.y + f.w * w3.y;
                acc[i][2] += f.x * w0.z + f.y * w1.z + f.z * w2.z + f.w * w3.z;
                acc[i][3] += f.x * w0.w + f.y * w1.w + f.z * w2.w + f.w * w3.w;
            }
        }
        __syncthreads();
    }
    float b0 = B[d0], b1 = B[d0 + 1], b2 = B[d0 + 2], b3 = B[d0 + 3];
    #pragma unroll
    for (int i = 0; i < 2; ++i) {
        acc[i][0] += b0; acc[i][1] += b1; acc[i][2] += b2; acc[i][3] += b3;
        float ss = acc[i][0] * acc[i][0] + acc[i][1] * acc[i][1]
                 + acc[i][2] * acc[i][2] + acc[i][3] * acc[i][3];
        #pragma unroll
        for (int m = 8; m >= 1; m >>= 1) ss += __shfl_xor(ss, m, 64);  // 16 lanes/row
        float scale = 1.0f / fmaxf(sqrtf(ss), 1e-12f);
        int gr = block_r0 + r0 + i;
        if (gr < NITEM) {
            ushort4 v4;
            v4.x = bf16r(acc[i][0] * scale);
            v4.y = bf16r(acc[i][1] * scale);
            v4.z = bf16r(acc[i][2] * scale);
            v4.w = bf16r(acc[i][3] * scale);
            *(ushort4*)&e0[(size_t)(NUSER + gr) * DL + d0] = v4;
        }
    }
}

// ---------------- pass 1: per-chunk histogram over row-bins ----------------
__global__ __launch_bounds__(256) void k_hist(const int* __restrict__ rows,
                                              int* __restrict__ cnt) {
    __shared__ int h[NB];
    int c = blockIdx.x, t = threadIdx.x;
    for (int i = t; i < NB; i += 256) h[i] = 0;
    __syncthreads();
    int end = (c + 1) * CHUNK;
    for (int e = c * CHUNK + t; e < end; e += 256)
        atomicAdd(&h[rows[e] >> 7], 1);
    __syncthreads();
    for (int i = t; i < NB; i += 256) cnt[c * NB + i] = h[i];
}

// ---------------- pass 2a: per-bin exclusive scan over chunks ----------------
__global__ __launch_bounds__(256) void k_scan1(const int* __restrict__ cnt,
                                               int* __restrict__ cntOff,
                                               int* __restrict__ binTot) {
    __shared__ int s[256];
    int b = blockIdx.x, t = threadIdx.x;
    int x = cnt[t * NB + b];
    s[t] = x;
    __syncthreads();
    #pragma unroll
    for (int off = 1; off < 256; off <<= 1) {
        int v = (t >= off) ? s[t - off] : 0;
        __syncthreads();
        s[t] += v;
        __syncthreads();
    }
    cntOff[t * NB + b] = s[t] - x;
    if (t == 255) binTot[b] = s[255];
}

// ---------------- pass 2b: exclusive scan of bin totals ----------------
__global__ __launch_bounds__(256) void k_scan2(const int* __restrict__ binTot,
                                               int* __restrict__ binBase) {
    __shared__ int s[256];
    __shared__ int carry;
    int t = threadIdx.x;
    if (t == 0) carry = 0;
    __syncthreads();
    for (int base = 0; base < NB; base += 256) {
        int idx = base + t;
        int x = (idx < NB) ? binTot[idx] : 0;
        s[t] = x;
        __syncthreads();
        #pragma unroll
        for (int off = 1; off < 256; off <<= 1) {
            int v = (t >= off) ? s[t - off] : 0;
            __syncthreads();
            s[t] += v;
            __syncthreads();
        }
        if (idx < NB) binBase[idx] = carry + s[t] - x;
        __syncthreads();
        if (t == 255) carry += s[255];
        __syncthreads();
    }
    if (t == 0) binBase[NB] = carry;   // == NNZ
}

// ---------------- pass 3: scatter edges into bin-partitioned list ----------------
__global__ __launch_bounds__(256) void k_scatter(const int* __restrict__ rows,
                                                 const int* __restrict__ cols,
                                                 const float* __restrict__ vals,
                                                 const int* __restrict__ cntOff,
                                                 const int* __restrict__ binBase,
                                                 int2* __restrict__ eb) {
    __shared__ int cur[NB];
    int c = blockIdx.x, t = threadIdx.x;
    for (int i = t; i < NB; i += 256) cur[i] = binBase[i] + cntOff[c * NB + i];
    __syncthreads();
    int end = (c + 1) * CHUNK;
    for (int e = c * CHUNK + t; e < end; e += 256) {
        int r = rows[e];
        int b = r >> 7;
        int pos = atomicAdd(&cur[b], 1);
        eb[pos] = make_int2(cols[e] | ((r & 127) << 18), __float_as_int(vals[e]));
    }
}

// ---------------- pass 4: per-bin counting sort -> exact row-sorted CSR ----------------
__global__ __launch_bounds__(256) void k_binsort(const int2* __restrict__ eb,
                                                 const int* __restrict__ binBase,
                                                 int2* __restrict__ eb2,
                                                 int2* __restrict__ rowSC) {
    __shared__ int h[128];
    __shared__ int s[128];
    int b = blockIdx.x, t = threadIdx.x;
    if (t < 128) h[t] = 0;
    __syncthreads();
    int base = binBase[b];
    int cnt  = binBase[b + 1] - base;
    for (int j = t; j < cnt; j += 256)
        atomicAdd(&h[eb[base + j].x >> 18], 1);
    __syncthreads();
    if (t < 128) s[t] = h[t];
    __syncthreads();
    #pragma unroll
    for (int off = 1; off < 128; off <<= 1) {
        int v = 0;
        if (t < 128 && t >= off) v = s[t - off];
        __syncthreads();
        if (t < 128) s[t] += v;
        __syncthreads();
    }
    if (t < 128) {
        int e = s[t] - h[t];       // exclusive within-bin offset
        int r = (b << 7) + t;
        if (r < NTOT) rowSC[r] = make_int2(base + e, h[t]);
        s[t] = e;                  // becomes the cursor
    }
    __syncthreads();
    for (int j = t; j < cnt; j += 256) {
        int2 e = eb[base + j];
        int rl = e.x >> 18;
        int pos = base + atomicAdd(&s[rl], 1);
        eb2[pos] = make_int2(e.x & 0x3FFFF, e.y);
    }
}

// ---------------- SpMM layer: wave per row, 8 groups, software-pipelined ----------------
__global__ __launch_bounds__(256) void k_spmm_row(const int2* __restrict__ rowSC,
                                                  const int2* __restrict__ eb2,
                                                  const unsigned short* __restrict__ embIn,
                                                  unsigned short* __restrict__ embOut) {
    int wid = (blockIdx.x * 256 + threadIdx.x) >> 6;
    if (wid >= NTOT) return;
    int lane = threadIdx.x & 63;
    int g = lane >> 3, ld = lane & 7;          // 8 groups x 8 lanes; lane covers 8 dims
    int2 sc = rowSC[wid];
    int end = sc.x + sc.y;
    float acc[8] = {};
    int j = sc.x + g;
    if (j < end) {
        int2 e = eb2[j];
        uint4 em = *(const uint4*)&embIn[(size_t)e.x * DL + ld * 8];
        j += 8;
        while (true) {
            bool more = j < end;
            int2 en; uint4 emn;
            if (more) {                         // issue next loads before FMAs
                en  = eb2[j];
                emn = *(const uint4*)&embIn[(size_t)en.x * DL + ld * 8];
            }
            float v = __int_as_float(e.y);
            const unsigned* pu = (const unsigned*)&em;
            #pragma unroll
            for (int k = 0; k < 4; ++k) {
                acc[2 * k]     += v * __uint_as_float(pu[k] << 16);
                acc[2 * k + 1] += v * __uint_as_float(pu[k] & 0xFFFF0000u);
            }
            if (!more) break;
            e = en; em = emn; j += 8;
        }
    }
    #pragma unroll
    for (int m = 8; m <= 32; m <<= 1) {
        #pragma unroll
        for (int k = 0; k < 8; ++k) acc[k] += __shfl_xor(acc[k], m, 64);
    }
    if (g == 0) {
        uint4 o;
        o.x = pack2(acc[0], acc[1]);
        o.y = pack2(acc[2], acc[3]);
        o.z = pack2(acc[4], acc[5]);
        o.w = pack2(acc[6], acc[7]);
        *(uint4*)&embOut[(size_t)wid * DL + ld * 8] = o;
    }
}

// ---------------- last layer: same + fused out = 0.25*(e0+e1+e2+acc) ----------------
__global__ __launch_bounds__(256) void k_spmm_last(const int2* __restrict__ rowSC,
                                                   const int2* __restrict__ eb2,
                                                   const unsigned short* __restrict__ e0,
                                                   const unsigned short* __restrict__ e1,
                                                   const unsigned short* __restrict__ e2,
                                                   float* __restrict__ out) {
    int wid = (blockIdx.x * 256 + threadIdx.x) >> 6;
    if (wid >= NTOT) return;
    int lane = threadIdx.x & 63;
    int g = lane >> 3, ld = lane & 7;
    int2 sc = rowSC[wid];
    int end = sc.x + sc.y;
    float acc[8] = {};
    int j = sc.x + g;
    if (j < end) {
        int2 e = eb2[j];
        uint4 em = *(const uint4*)&e2[(size_t)e.x * DL + ld * 8];
        j += 8;
        while (true) {
            bool more = j < end;
            int2 en; uint4 emn;
            if (more) {
                en  = eb2[j];
                emn = *(const uint4*)&e2[(size_t)en.x * DL + ld * 8];
            }
            float v = __int_as_float(e.y);
            const unsigned* pu = (const unsigned*)&em;
            #pragma unroll
            for (int k = 0; k < 4; ++k) {
                acc[2 * k]     += v * __uint_as_float(pu[k] << 16);
                acc[2 * k + 1] += v * __uint_as_float(pu[k] & 0xFFFF0000u);
            }
            if (!more) break;
            e = en; em = emn; j += 8;
        }
    }
    #pragma unroll
    for (int m = 8; m <= 32; m <<= 1) {
        #pragma unroll
        for (int k = 0; k < 8; ++k) acc[k] += __shfl_xor(acc[k], m, 64);
    }
    if (g == 0) {
        size_t o = (size_t)wid * DL + ld * 8;
        uint4 a = *(const uint4*)&e0[o];
        uint4 b = *(const uint4*)&e1[o];
        uint4 c = *(const uint4*)&e2[o];
        const unsigned* pa = (const unsigned*)&a;
        const unsigned* pb = (const unsigned*)&b;
        const unsigned* pc = (const unsigned*)&c;
        float r[8];
        #pragma unroll
        for (int k = 0; k < 4; ++k) {
            float lo = __uint_as_float(pa[k] << 16) + __uint_as_float(pb[k] << 16)
                     + __uint_as_float(pc[k] << 16) + acc[2 * k];
            float hi = __uint_as_float(pa[k] & 0xFFFF0000u) + __uint_as_float(pb[k] & 0xFFFF0000u)
                     + __uint_as_float(pc[k] & 0xFFFF0000u) + acc[2 * k + 1];
            r[2 * k]     = 0.25f * lo;
            r[2 * k + 1] = 0.25f * hi;
        }
        *(float4*)&out[o]     = make_float4(r[0], r[1], r[2], r[3]);
        *(float4*)&out[o + 4] = make_float4(r[4], r[5], r[6], r[7]);
    }
}

extern "C" void kernel_launch(void* const* d_in, const int* in_sizes, int n_in,
                              void* d_out, int out_size, void* d_ws, size_t ws_size,
                              hipStream_t stream) {
    const float* F    = (const float*)d_in[0];
    const float* UP   = (const float*)d_in[1];
    const float* W    = (const float*)d_in[2];
    const float* B    = (const float*)d_in[3];
    const int*   rows = (const int*)d_in[4];
    const int*   cols = (const int*)d_in[5];
    const float* vals = (const float*)d_in[6];
    float* out = (float*)d_out;

    // workspace carve (~100 MB)
    unsigned short* e0 = (unsigned short*)d_ws;
    unsigned short* e1 = e0 + (size_t)NTOT * DL;
    unsigned short* e2 = e1 + (size_t)NTOT * DL;
    int2* eb      = (int2*)(e2 + (size_t)NTOT * DL);
    int2* eb2     = eb + (size_t)NNZ_;
    int2* rowSC   = eb2 + (size_t)NNZ_;
    int*  cnt     = (int*)(rowSC + NTOT);
    int*  cntOff  = cnt + (size_t)NCHUNK * NB;
    int*  binTot  = cntOff + (size_t)NCHUNK * NB;
    int*  binBase = binTot + NB;   // NB+1 entries

    k_user<<<(NUSER * DL) / 256, 256, 0, stream>>>(UP, e0);
    k_item<<<(NITEM + 63) / 64, 512, 0, stream>>>(F, W, B, e0);
    k_hist<<<NCHUNK, 256, 0, stream>>>(rows, cnt);
    k_scan1<<<NB, 256, 0, stream>>>(cnt, cntOff, binTot);
    k_scan2<<<1, 256, 0, stream>>>(binTot, binBase);
    k_scatter<<<NCHUNK, 256, 0, stream>>>(rows, cols, vals, cntOff, binBase, eb);
    k_binsort<<<NB, 256, 0, stream>>>(eb, binBase, eb2, rowSC);

    k_spmm_row<<<(NTOT * DL) / 256, 256, 0, stream>>>(rowSC, eb2, e0, e1);
    k_spmm_row<<<(NTOT * DL) / 256, 256, 0, stream>>>(rowSC, eb2, e1, e2);
    k_spmm_last<<<(NTOT * DL) / 256, 256, 0, stream>>>(rowSC, eb2, e0, e1, e2, out);
}

// Round 6
// 367.766 us; speedup vs baseline: 1.0849x; 1.0849x over previous
//
#include <hip/hip_runtime.h>

#define NUSER 100000
#define NITEM 50000
#define NTOT  150000
#define DF    512
#define DL    64
#define NNZ_  2400000
#define NB    1172        // ceil(150000/128) row-bins of 128 rows
#define NCHUNK 256
#define CHUNK  9375       // 256*9375 = 2,400,000 exactly

typedef short bf16x8 __attribute__((ext_vector_type(8)));
typedef float f32x4  __attribute__((ext_vector_type(4)));

__device__ __forceinline__ unsigned short bf16r(float f) {
    unsigned u = __float_as_uint(f);
    return (unsigned short)((u + 0x7FFFu + ((u >> 16) & 1u)) >> 16);
}
__device__ __forceinline__ unsigned pack2(float lo, float hi) {
    return (unsigned)bf16r(lo) | ((unsigned)bf16r(hi) << 16);
}

// ---------------- users: L2-normalize rows -> e0 (bf16) ----------------
__global__ __launch_bounds__(256) void k_user(const float* __restrict__ up,
                                              unsigned short* __restrict__ e0) {
    int t = blockIdx.x * 256 + threadIdx.x;
    float v = up[t];
    float ss = v * v;
    #pragma unroll
    for (int m = 32; m >= 1; m >>= 1) ss += __shfl_xor(ss, m, 64);
    float scale = 1.0f / fmaxf(sqrtf(ss), 1e-12f);
    e0[t] = bf16r(v * scale);
}

// ---------------- W -> bf16 transposed [64][512] in ws ----------------
__global__ __launch_bounds__(256) void k_wt2(const float* __restrict__ W,
                                             unsigned short* __restrict__ Wtb) {
    int idx = blockIdx.x * 256 + threadIdx.x;   // 0..32767
    int k = idx >> 6, d = idx & 63;
    Wtb[d * DF + k] = bf16r(W[idx]);
}

// ---------------- items: MFMA bf16 GEMM, wave = 16 rows x 64 dims ----------------
__global__ __launch_bounds__(256) void k_item(const float* __restrict__ F,
                                              const unsigned short* __restrict__ Wtb,
                                              const float* __restrict__ B,
                                              unsigned short* __restrict__ e0) {
    int t = threadIdx.x;
    int w = t >> 6, lane = t & 63;
    int g = lane >> 4;          // k-chunk group 0..3
    int c = lane & 15;          // A-row / B-col / C-col index
    int row_base = blockIdx.x * 64 + w * 16;

    int ar = row_base + c;
    if (ar >= NITEM) ar = NITEM - 1;            // clamp OOB loads; stores guarded later
    const float* Frow = F + (size_t)ar * DF;

    f32x4 acc[4] = {};                          // 4 col-tiles of 16x16
    #pragma unroll 2
    for (int kc = 0; kc < DF; kc += 32) {
        int k0 = kc + g * 8;
        float4 f0 = *(const float4*)&Frow[k0];
        float4 f1 = *(const float4*)&Frow[k0 + 4];
        union { uint4 u; bf16x8 v; } a;
        a.u.x = pack2(f0.x, f0.y);
        a.u.y = pack2(f0.z, f0.w);
        a.u.z = pack2(f1.x, f1.y);
        a.u.w = pack2(f1.z, f1.w);
        #pragma unroll
        for (int ct = 0; ct < 4; ++ct) {
            union { uint4 u; bf16x8 v; } b;
            b.u = *(const uint4*)&Wtb[(size_t)(ct * 16 + c) * DF + k0];
            acc[ct] = __builtin_amdgcn_mfma_f32_16x16x32_bf16(a.v, b.v, acc[ct], 0, 0, 0);
        }
    }

    // bias
    #pragma unroll
    for (int ct = 0; ct < 4; ++ct) {
        float bc = B[ct * 16 + c];
        #pragma unroll
        for (int r = 0; r < 4; ++r) acc[ct][r] += bc;
    }
    // row sum-of-squares: reduce across the 16 lanes of this k-group (cols 0..15 x 4 tiles)
    float ssv[4];
    #pragma unroll
    for (int r = 0; r < 4; ++r) {
        float s = acc[0][r] * acc[0][r] + acc[1][r] * acc[1][r]
                + acc[2][r] * acc[2][r] + acc[3][r] * acc[3][r];
        #pragma unroll
        for (int m = 1; m <= 8; m <<= 1) s += __shfl_xor(s, m, 64);
        ssv[r] = 1.0f / fmaxf(sqrtf(s), 1e-12f);
    }
    // store: row = g*4 + r, col = ct*16 + c
    #pragma unroll
    for (int r = 0; r < 4; ++r) {
        int gr = row_base + g * 4 + r;
        if (gr < NITEM) {
            size_t o = (size_t)(NUSER + gr) * DL + c;
            #pragma unroll
            for (int ct = 0; ct < 4; ++ct)
                e0[o + ct * 16] = bf16r(acc[ct][r] * ssv[r]);
        }
    }
}

// ---------------- pass 1: per-chunk histogram over row-bins ----------------
__global__ __launch_bounds__(256) void k_hist(const int* __restrict__ rows,
                                              int* __restrict__ cnt) {
    __shared__ int h[NB];
    int c = blockIdx.x, t = threadIdx.x;
    for (int i = t; i < NB; i += 256) h[i] = 0;
    __syncthreads();
    int end = (c + 1) * CHUNK;
    for (int e = c * CHUNK + t; e < end; e += 256)
        atomicAdd(&h[rows[e] >> 7], 1);
    __syncthreads();
    for (int i = t; i < NB; i += 256) cnt[c * NB + i] = h[i];
}

// ---------------- pass 2a: per-bin exclusive scan over chunks ----------------
__global__ __launch_bounds__(256) void k_scan1(const int* __restrict__ cnt,
                                               int* __restrict__ cntOff,
                                               int* __restrict__ binTot) {
    __shared__ int s[256];
    int b = blockIdx.x, t = threadIdx.x;
    int x = cnt[t * NB + b];
    s[t] = x;
    __syncthreads();
    #pragma unroll
    for (int off = 1; off < 256; off <<= 1) {
        int v = (t >= off) ? s[t - off] : 0;
        __syncthreads();
        s[t] += v;
        __syncthreads();
    }
    cntOff[t * NB + b] = s[t] - x;
    if (t == 255) binTot[b] = s[255];
}

// ---------------- pass 2b: exclusive scan of bin totals ----------------
__global__ __launch_bounds__(256) void k_scan2(const int* __restrict__ binTot,
                                               int* __restrict__ binBase) {
    __shared__ int s[256];
    __shared__ int carry;
    int t = threadIdx.x;
    if (t == 0) carry = 0;
    __syncthreads();
    for (int base = 0; base < NB; base += 256) {
        int idx = base + t;
        int x = (idx < NB) ? binTot[idx] : 0;
        s[t] = x;
        __syncthreads();
        #pragma unroll
        for (int off = 1; off < 256; off <<= 1) {
            int v = (t >= off) ? s[t - off] : 0;
            __syncthreads();
            s[t] += v;
            __syncthreads();
        }
        if (idx < NB) binBase[idx] = carry + s[t] - x;
        __syncthreads();
        if (t == 255) carry += s[255];
        __syncthreads();
    }
    if (t == 0) binBase[NB] = carry;   // == NNZ
}

// ---------------- pass 3: scatter edges into bin-partitioned list ----------------
__global__ __launch_bounds__(256) void k_scatter(const int* __restrict__ rows,
                                                 const int* __restrict__ cols,
                                                 const float* __restrict__ vals,
                                                 const int* __restrict__ cntOff,
                                                 const int* __restrict__ binBase,
                                                 int2* __restrict__ eb) {
    __shared__ int cur[NB];
    int c = blockIdx.x, t = threadIdx.x;
    for (int i = t; i < NB; i += 256) cur[i] = binBase[i] + cntOff[c * NB + i];
    __syncthreads();
    int end = (c + 1) * CHUNK;
    for (int e = c * CHUNK + t; e < end; e += 256) {
        int r = rows[e];
        int b = r >> 7;
        int pos = atomicAdd(&cur[b], 1);
        eb[pos] = make_int2(cols[e] | ((r & 127) << 18), __float_as_int(vals[e]));
    }
}

// ---------------- pass 4: per-bin counting sort -> exact row-sorted CSR ----------------
__global__ __launch_bounds__(256) void k_binsort(const int2* __restrict__ eb,
                                                 const int* __restrict__ binBase,
                                                 int2* __restrict__ eb2,
                                                 int2* __restrict__ rowSC) {
    __shared__ int h[128];
    __shared__ int s[128];
    int b = blockIdx.x, t = threadIdx.x;
    if (t < 128) h[t] = 0;
    __syncthreads();
    int base = binBase[b];
    int cnt  = binBase[b + 1] - base;
    for (int j = t; j < cnt; j += 256)
        atomicAdd(&h[eb[base + j].x >> 18], 1);
    __syncthreads();
    if (t < 128) s[t] = h[t];
    __syncthreads();
    #pragma unroll
    for (int off = 1; off < 128; off <<= 1) {
        int v = 0;
        if (t < 128 && t >= off) v = s[t - off];
        __syncthreads();
        if (t < 128) s[t] += v;
        __syncthreads();
    }
    if (t < 128) {
        int e = s[t] - h[t];       // exclusive within-bin offset
        int r = (b << 7) + t;
        if (r < NTOT) rowSC[r] = make_int2(base + e, h[t]);
        s[t] = e;                  // becomes the cursor
    }
    __syncthreads();
    for (int j = t; j < cnt; j += 256) {
        int2 e = eb[base + j];
        int rl = e.x >> 18;
        int pos = base + atomicAdd(&s[rl], 1);
        eb2[pos] = make_int2(e.x & 0x3FFFF, e.y);
    }
}

// ---------------- SpMM layer: wave per row, 8 groups, software-pipelined ----------------
__global__ __launch_bounds__(256) void k_spmm_row(const int2* __restrict__ rowSC,
                                                  const int2* __restrict__ eb2,
                                                  const unsigned short* __restrict__ embIn,
                                                  unsigned short* __restrict__ embOut) {
    int wid = (blockIdx.x * 256 + threadIdx.x) >> 6;
    if (wid >= NTOT) return;
    int lane = threadIdx.x & 63;
    int g = lane >> 3, ld = lane & 7;          // 8 groups x 8 lanes; lane covers 8 dims
    int2 sc = rowSC[wid];
    int end = sc.x + sc.y;
    float acc[8] = {};
    int j = sc.x + g;
    if (j < end) {
        int2 e = eb2[j];
        uint4 em = *(const uint4*)&embIn[(size_t)e.x * DL + ld * 8];
        j += 8;
        while (true) {
            bool more = j < end;
            int2 en; uint4 emn;
            if (more) {                         // issue next loads before FMAs
                en  = eb2[j];
                emn = *(const uint4*)&embIn[(size_t)en.x * DL + ld * 8];
            }
            float v = __int_as_float(e.y);
            const unsigned* pu = (const unsigned*)&em;
            #pragma unroll
            for (int k = 0; k < 4; ++k) {
                acc[2 * k]     += v * __uint_as_float(pu[k] << 16);
                acc[2 * k + 1] += v * __uint_as_float(pu[k] & 0xFFFF0000u);
            }
            if (!more) break;
            e = en; em = emn; j += 8;
        }
    }
    #pragma unroll
    for (int m = 8; m <= 32; m <<= 1) {
        #pragma unroll
        for (int k = 0; k < 8; ++k) acc[k] += __shfl_xor(acc[k], m, 64);
    }
    if (g == 0) {
        uint4 o;
        o.x = pack2(acc[0], acc[1]);
        o.y = pack2(acc[2], acc[3]);
        o.z = pack2(acc[4], acc[5]);
        o.w = pack2(acc[6], acc[7]);
        *(uint4*)&embOut[(size_t)wid * DL + ld * 8] = o;
    }
}

// ---------------- last layer: same + fused out = 0.25*(e0+e1+e2+acc) ----------------
__global__ __launch_bounds__(256) void k_spmm_last(const int2* __restrict__ rowSC,
                                                   const int2* __restrict__ eb2,
                                                   const unsigned short* __restrict__ e0,
                                                   const unsigned short* __restrict__ e1,
                                                   const unsigned short* __restrict__ e2,
                                                   float* __restrict__ out) {
    int wid = (blockIdx.x * 256 + threadIdx.x) >> 6;
    if (wid >= NTOT) return;
    int lane = threadIdx.x & 63;
    int g = lane >> 3, ld = lane & 7;
    int2 sc = rowSC[wid];
    int end = sc.x + sc.y;
    float acc[8] = {};
    int j = sc.x + g;
    if (j < end) {
        int2 e = eb2[j];
        uint4 em = *(const uint4*)&e2[(size_t)e.x * DL + ld * 8];
        j += 8;
        while (true) {
            bool more = j < end;
            int2 en; uint4 emn;
            if (more) {
                en  = eb2[j];
                emn = *(const uint4*)&e2[(size_t)en.x * DL + ld * 8];
            }
            float v = __int_as_float(e.y);
            const unsigned* pu = (const unsigned*)&em;
            #pragma unroll
            for (int k = 0; k < 4; ++k) {
                acc[2 * k]     += v * __uint_as_float(pu[k] << 16);
                acc[2 * k + 1] += v * __uint_as_float(pu[k] & 0xFFFF0000u);
            }
            if (!more) break;
            e = en; em = emn; j += 8;
        }
    }
    #pragma unroll
    for (int m = 8; m <= 32; m <<= 1) {
        #pragma unroll
        for (int k = 0; k < 8; ++k) acc[k] += __shfl_xor(acc[k], m, 64);
    }
    if (g == 0) {
        size_t o = (size_t)wid * DL + ld * 8;
        uint4 a = *(const uint4*)&e0[o];
        uint4 b = *(const uint4*)&e1[o];
        uint4 c = *(const uint4*)&e2[o];
        const unsigned* pa = (const unsigned*)&a;
        const unsigned* pb = (const unsigned*)&b;
        const unsigned* pc = (const unsigned*)&c;
        float r[8];
        #pragma unroll
        for (int k = 0; k < 4; ++k) {
            float lo = __uint_as_float(pa[k] << 16) + __uint_as_float(pb[k] << 16)
                     + __uint_as_float(pc[k] << 16) + acc[2 * k];
            float hi = __uint_as_float(pa[k] & 0xFFFF0000u) + __uint_as_float(pb[k] & 0xFFFF0000u)
                     + __uint_as_float(pc[k] & 0xFFFF0000u) + acc[2 * k + 1];
            r[2 * k]     = 0.25f * lo;
            r[2 * k + 1] = 0.25f * hi;
        }
        *(float4*)&out[o]     = make_float4(r[0], r[1], r[2], r[3]);
        *(float4*)&out[o + 4] = make_float4(r[4], r[5], r[6], r[7]);
    }
}

extern "C" void kernel_launch(void* const* d_in, const int* in_sizes, int n_in,
                              void* d_out, int out_size, void* d_ws, size_t ws_size,
                              hipStream_t stream) {
    const float* F    = (const float*)d_in[0];
    const float* UP   = (const float*)d_in[1];
    const float* W    = (const float*)d_in[2];
    const float* B    = (const float*)d_in[3];
    const int*   rows = (const int*)d_in[4];
    const int*   cols = (const int*)d_in[5];
    const float* vals = (const float*)d_in[6];
    float* out = (float*)d_out;

    // workspace carve (~100 MB)
    unsigned short* e0 = (unsigned short*)d_ws;
    unsigned short* e1 = e0 + (size_t)NTOT * DL;
    unsigned short* e2 = e1 + (size_t)NTOT * DL;
    int2* eb      = (int2*)(e2 + (size_t)NTOT * DL);
    int2* eb2     = eb + (size_t)NNZ_;
    int2* rowSC   = eb2 + (size_t)NNZ_;
    int*  cnt     = (int*)(rowSC + NTOT);
    int*  cntOff  = cnt + (size_t)NCHUNK * NB;
    int*  binTot  = cntOff + (size_t)NCHUNK * NB;
    int*  binBase = binTot + NB;                      // NB+1 entries
    unsigned short* Wtb = (unsigned short*)(binBase + NB + 1);  // 64x512 bf16

    k_wt2<<<(DF * DL) / 256, 256, 0, stream>>>(W, Wtb);
    k_user<<<(NUSER * DL) / 256, 256, 0, stream>>>(UP, e0);
    k_item<<<(NITEM + 63) / 64, 256, 0, stream>>>(F, Wtb, B, e0);
    k_hist<<<NCHUNK, 256, 0, stream>>>(rows, cnt);
    k_scan1<<<NB, 256, 0, stream>>>(cnt, cntOff, binTot);
    k_scan2<<<1, 256, 0, stream>>>(binTot, binBase);
    k_scatter<<<NCHUNK, 256, 0, stream>>>(rows, cols, vals, cntOff, binBase, eb);
    k_binsort<<<NB, 256, 0, stream>>>(eb, binBase, eb2, rowSC);

    k_spmm_row<<<(NTOT * DL) / 256, 256, 0, stream>>>(rowSC, eb2, e0, e1);
    k_spmm_row<<<(NTOT * DL) / 256, 256, 0, stream>>>(rowSC, eb2, e1, e2);
    k_spmm_last<<<(NTOT * DL) / 256, 256, 0, stream>>>(rowSC, eb2, e0, e1, e2, out);
}